// Round 13
// baseline (191.151 us; speedup 1.0000x reference)
//
#include <hip/hip_runtime.h>
#include <math.h>

#define NTOK   16384
#define DIM    2048
#define NEXP   64
#define TOPK   8
#define TB     16          // tokens per block -> grid 1024
#define KC     64          // K chunk
#define NCHUNK (DIM / KC)  // 32

typedef int    v4i __attribute__((ext_vector_type(4)));
typedef double v4d __attribute__((ext_vector_type(4)));

// ws layout: [0,512) pinv (64 f64); [512, 512+786432) proto limb dwords
#define WS_NEEDED (512 + (size_t)NEXP * 6 * (DIM / 4) * 4)

// x digit scales: Xi = rint(r * 2^(3+7i)), weight 2^-(3+7i), |Xi|<=64
__device__ __constant__ float XSC[6] = {8.f, 1024.f, 131072.f, 16777216.f, 2147483648.f, 274877906944.f};
__device__ __constant__ float XWN[6] = {-0.125f, -9.765625e-04f, -7.62939453125e-06f,
                                        -5.9604644775390625e-08f, -4.656612873077393e-10f,
                                        -3.637978807091713e-12f};
// p digit scales: Yj = rint(r * 2^(9+7j)), weight 2^-(9+7j)
__device__ __constant__ float PSC[6] = {512.f, 65536.f, 8388608.f, 1073741824.f, 137438953472.f, 17592186044416.f};
__device__ __constant__ float PWN[6] = {-1.953125e-03f, -1.52587890625e-05f, -1.1920928955078125e-07f,
                                        -9.31322574615478516e-10f, -7.27595761418342590e-12f,
                                        -5.68434188608080149e-14f};
// class-combine weights 2^(-12-7d), d=0..6
__device__ __constant__ double CWD[7] = {2.44140625e-04, 1.9073486328125e-06, 1.490116119384765625e-08,
                                         1.16415321826934814e-10, 9.09494701772928238e-13,
                                         7.10542735760100186e-15, 5.55111512312578270e-17};

// ---------------- pre-kernel: pinv (f64) + proto limb decomposition ----------------
__global__ __launch_bounds__(64) void proto_prep_kernel(
    const float* __restrict__ proto, double* __restrict__ pinv,
    int* __restrict__ plimb)
{
    const int e = blockIdx.x, t = threadIdx.x;
    const float* row = proto + (size_t)e * DIM;
    const int k0 = t * 32;                      // contiguous 32-k segment
    double s = 0.0;
#pragma unroll
    for (int g = 0; g < 8; ++g) {               // 8 dword-groups of 4 k
        int pk0 = 0, pk1 = 0, pk2 = 0, pk3 = 0, pk4 = 0, pk5 = 0;
#pragma unroll
        for (int b = 0; b < 4; ++b) {
            float f = row[k0 + g * 4 + b];
            s += (double)f * (double)f;
            float r = f;
#pragma unroll
            for (int j = 0; j < 6; ++j) {
                float rd = rintf(r * PSC[j]);
                int   d  = (int)rd;
                r = fmaf(rd, PWN[j], r);        // exact residual update
                int byte = (d & 255) << (8 * b);
                if (j == 0) pk0 |= byte; else if (j == 1) pk1 |= byte;
                else if (j == 2) pk2 |= byte;   else if (j == 3) pk3 |= byte;
                else if (j == 4) pk4 |= byte;   else pk5 |= byte;
            }
        }
        const int dw = (k0 + g * 4) >> 2;       // dword index within row
        plimb[(e * 6 + 0) * (DIM / 4) + dw] = pk0;
        plimb[(e * 6 + 1) * (DIM / 4) + dw] = pk1;
        plimb[(e * 6 + 2) * (DIM / 4) + dw] = pk2;
        plimb[(e * 6 + 3) * (DIM / 4) + dw] = pk3;
        plimb[(e * 6 + 4) * (DIM / 4) + dw] = pk4;
        plimb[(e * 6 + 5) * (DIM / 4) + dw] = pk5;
    }
#pragma unroll
    for (int d = 1; d < 64; d <<= 1)
        s += __shfl_xor(s, d, 64);
    if (t == 0)
        pinv[e] = 1.0 / fmax(sqrt(s), 1e-12);
}

// ---------------- main: exact-integer i8-MFMA router ----------------
__global__ __launch_bounds__(256, 2) void router_i8_kernel(
    const float* __restrict__ x, const double* __restrict__ pinv,
    const int* __restrict__ plimb, float* __restrict__ out)
{
    __shared__ float  logits[TB][NEXP];
    __shared__ double xinv_lds[TB];
    __shared__ double pinv_lds[NEXP];

    const int tid  = threadIdx.x;
    const int lane = tid & 63;
    const int w    = tid >> 6;            // wave = expert tile [16w,16w+16)
    const int tok0 = blockIdx.x * TB;
    const int arow = lane & 15;           // A-row / B-col label
    const int akg  = lane >> 4;           // quarter-wave k-group

    // per-lane pointers: x row (16 floats/chunk), B limbs (dwords)
    const float* xrow  = x + (size_t)(tok0 + arow) * DIM + akg * 16;
    const int    ecol  = w * 16 + arow;
    const int*   bbase = plimb + (size_t)ecol * 6 * (DIM / 4) + akg * 4;

    v4i acc[7];
#pragma unroll
    for (int d = 0; d < 7; ++d) acc[d] = (v4i){0, 0, 0, 0};
    double sumsq = 0.0;

    float4 xa[4], xb[4];
    v4i bf[6];

    auto loadx = [&](float4 (&xq)[4], int c) {
        const float* p = xrow + c * KC;
#pragma unroll
        for (int g = 0; g < 4; ++g) xq[g] = *(const float4*)(p + 4 * g);
    };
    auto loadb = [&](int c) {
#pragma unroll
        for (int j = 0; j < 6; ++j)
            bf[j] = *(const v4i*)(bbase + j * (DIM / 4) + c * 16);
    };
    auto process = [&](float4 (&xq)[4]) {
        int apack[6][4];
#pragma unroll
        for (int g = 0; g < 4; ++g) {
#pragma unroll
            for (int b = 0; b < 4; ++b) {
                float f = (b == 0) ? xq[g].x : (b == 1) ? xq[g].y
                        : (b == 2) ? xq[g].z : xq[g].w;
                sumsq += (double)f * (double)f;
                float r = f;
#pragma unroll
                for (int i2 = 0; i2 < 6; ++i2) {
                    float rd = rintf(r * XSC[i2]);
                    int   d  = (int)rd;
                    r = fmaf(rd, XWN[i2], r);         // exact
                    if (b == 0) apack[i2][g] = (d & 255);
                    else        apack[i2][g] |= (d & 255) << (8 * b);
                }
            }
        }
        // 26 class MFMAs: class d = i2 + j, exact i32 accumulate
#pragma unroll
        for (int j = 0; j < 6; ++j) {
#pragma unroll
            for (int i2 = 0; i2 < 6; ++i2) {
                if (i2 + j <= 6) {
                    v4i a = (v4i){apack[i2][0], apack[i2][1], apack[i2][2], apack[i2][3]};
                    acc[i2 + j] = __builtin_amdgcn_mfma_i32_16x16x64_i8(a, bf[j], acc[i2 + j], 0, 0, 0);
                }
            }
        }
    };

    if (tid < NEXP) pinv_lds[tid] = pinv[tid];

    // ---- barrier-free main loop, unroll-by-2, x double-buffered ----
    loadx(xa, 0);
    for (int c = 0; c < NCHUNK; c += 2) {
        loadb(c);
        loadx(xb, c + 1);
        process(xa);                       // decomp (~1.4k cyc) hides loads
        loadb(c + 1);
        if (c + 2 < NCHUNK) loadx(xa, c + 2);
        process(xb);
    }

    // ---- xinv: butterfly over the 4 k-quarters (r12 pattern) ----
    sumsq += __shfl_xor(sumsq, 16, 64);
    sumsq += __shfl_xor(sumsq, 32, 64);
    if (akg == 0)                          // identical bits across waves -> benign
        xinv_lds[arow] = 1.0 / fmax(sqrt(sumsq), 1e-12);

    // ---- i32 layout calibration: (lane,reg) -> (row,col) labels ----
    const int ones = 0x01010101;
    v4i onesv = (v4i){ones, ones, ones, ones};
    int rp = arow * ones;
    v4i rowv = (v4i){rp, rp, rp, rp};
    v4i c1 = (v4i){0, 0, 0, 0}, c2 = (v4i){0, 0, 0, 0};
    c1 = __builtin_amdgcn_mfma_i32_16x16x64_i8(rowv, onesv, c1, 0, 0, 0);  // 64*row
    c2 = __builtin_amdgcn_mfma_i32_16x16x64_i8(onesv, rowv, c2, 0, 0, 0);  // 64*col
    __syncthreads();

    // ---- combine classes in f64, scale to cosine logits, cast fp32 ----
#pragma unroll
    for (int i = 0; i < 4; ++i) {
        double S = 0.0;
#pragma unroll
        for (int d = 0; d < 7; ++d)
            S = fma((double)acc[d][i], CWD[d], S);
        const int tr = c1[i] >> 6;                 // token-within-tile label
        const int ec = c2[i] >> 6;                 // expert-within-16 label
        const int e  = w * 16 + ec;
        logits[tr][e] = (float)(S * xinv_lds[tr] * pinv_lds[e]);
    }
    __syncthreads();

    // ---- epilogue: np fp32 softmax bit-chain + rank by (w32 desc, idx asc) ----
#pragma unroll 1
    for (int i = 0; i < 4; ++i) {
        const int tl = w * 4 + i;
        const float l32 = logits[tl][lane];

        float m = l32;
#pragma unroll
        for (int d = 1; d < 64; d <<= 1) {
            float o = __shfl_xor(m, d, 64);
            m = fmaxf(m, o);
        }
        const float dd = l32 - m;
        const float e32 = (float)exp((double)dd);

        float r[8];
#pragma unroll
        for (int j = 0; j < 8; ++j) {
            float rj = __shfl(e32, j, 64);
#pragma unroll
            for (int b = 1; b < 8; ++b)
                rj += __shfl(e32, j + 8 * b, 64);
            r[j] = rj;
        }
        const float S = ((r[0] + r[1]) + (r[2] + r[3])) +
                        ((r[4] + r[5]) + (r[6] + r[7]));
        const float wgt = e32 / S;

        int rank = 0;
#pragma unroll 1
        for (int sdist = 1; sdist < 64; ++sdist) {
            float ow = __shfl_xor(wgt, sdist, 64);
            int j = lane ^ sdist;
            rank += (ow > wgt) || (ow == wgt && j < lane);
        }

        if (rank < TOPK) {
            const int tok = tok0 + tl;
            out[tok * TOPK + rank] = wgt;
            out[NTOK * TOPK + tok * TOPK + rank] = (float)lane;
        }
    }
}

// ---------------- fallback: proven r12 f64-MFMA kernel (ws too small) ----------------
__global__ __launch_bounds__(256, 2) void router_f64_kernel(
    const float* __restrict__ x, const float* __restrict__ proto,
    float* __restrict__ out)
{
    __shared__ float  logits[TB][NEXP];
    __shared__ double xinv_lds[TB];
    __shared__ double pinv_lds[NEXP];

    const int tid  = threadIdx.x;
    const int lane = tid & 63;
    const int w    = tid >> 6;
    const int tok0 = blockIdx.x * TB;
    const int etile = w;
    const int arow  = lane & 15;
    const int akg   = lane >> 4;
    const int kbase = akg * 8;

    v4d acc0 = {0., 0., 0., 0.}, acc1 = {0., 0., 0., 0.};
    v4d acc2 = {0., 0., 0., 0.}, acc3 = {0., 0., 0., 0.};
    double sumsq = 0.0, psq = 0.0;

    const float* xrow = x     + (size_t)(tok0 + arow)       * DIM + kbase;
    const float* prow = proto + (size_t)(etile * 16 + arow) * DIM + kbase;

    float4 xa0, xa1, pa0, pa1, xb0, xb1, pb0, pb1;

#define FLOADSET(X0, X1, P0, P1, c) do {                            \
    const float* _xp = xrow + (c) * 32;                             \
    const float* _pp = prow + (c) * 32;                             \
    X0 = *(const float4*)(_xp);  X1 = *(const float4*)(_xp + 4);    \
    P0 = *(const float4*)(_pp);  P1 = *(const float4*)(_pp + 4);    \
    } while (0)
#define FNORMQ(A, B) do {                                           \
    double a0 = (double)A.x, a1 = (double)A.y,                      \
           a2 = (double)A.z, a3 = (double)A.w;                      \
    double u0 = (double)B.x, u1 = (double)B.y,                      \
           u2 = (double)B.z, u3 = (double)B.w;                      \
    sumsq += a0*a0 + a1*a1 + a2*a2 + a3*a3;                         \
    psq   += u0*u0 + u1*u1 + u2*u2 + u3*u3;                         \
    } while (0)
#define FCOMPUTE(X0, X1, P0, P1) do {                               \
    FNORMQ(X0, P0); FNORMQ(X1, P1);                                 \
    acc0 = __builtin_amdgcn_mfma_f64_16x16x4f64((double)X0.x, (double)P0.x, acc0, 0, 0, 0); \
    acc1 = __builtin_amdgcn_mfma_f64_16x16x4f64((double)X0.y, (double)P0.y, acc1, 0, 0, 0); \
    acc2 = __builtin_amdgcn_mfma_f64_16x16x4f64((double)X0.z, (double)P0.z, acc2, 0, 0, 0); \
    acc3 = __builtin_amdgcn_mfma_f64_16x16x4f64((double)X0.w, (double)P0.w, acc3, 0, 0, 0); \
    acc0 = __builtin_amdgcn_mfma_f64_16x16x4f64((double)X1.x, (double)P1.x, acc0, 0, 0, 0); \
    acc1 = __builtin_amdgcn_mfma_f64_16x16x4f64((double)X1.y, (double)P1.y, acc1, 0, 0, 0); \
    acc2 = __builtin_amdgcn_mfma_f64_16x16x4f64((double)X1.z, (double)P1.z, acc2, 0, 0, 0); \
    acc3 = __builtin_amdgcn_mfma_f64_16x16x4f64((double)X1.w, (double)P1.w, acc3, 0, 0, 0); \
    } while (0)

    FLOADSET(xa0, xa1, pa0, pa1, 0);
    for (int c = 0; c < 64; c += 2) {
        FLOADSET(xb0, xb1, pb0, pb1, c + 1);
        FCOMPUTE(xa0, xa1, pa0, pa1);
        if (c + 2 < 64) FLOADSET(xa0, xa1, pa0, pa1, c + 2);
        FCOMPUTE(xb0, xb1, pb0, pb1);
    }
    const v4d acc = (acc0 + acc1) + (acc2 + acc3);

    sumsq += __shfl_xor(sumsq, 16, 64);
    sumsq += __shfl_xor(sumsq, 32, 64);
    psq   += __shfl_xor(psq, 16, 64);
    psq   += __shfl_xor(psq, 32, 64);
    if (akg == 0) {
        xinv_lds[arow]              = 1.0 / fmax(sqrt(sumsq), 1e-12);
        pinv_lds[etile * 16 + arow] = 1.0 / fmax(sqrt(psq), 1e-12);
    }
    v4d c1 = {0., 0., 0., 0.}, c2 = {0., 0., 0., 0.};
    c1 = __builtin_amdgcn_mfma_f64_16x16x4f64((double)arow, 1.0, c1, 0, 0, 0);
    c2 = __builtin_amdgcn_mfma_f64_16x16x4f64(1.0, (double)arow, c2, 0, 0, 0);
    __syncthreads();
#pragma unroll
    for (int i = 0; i < 4; ++i) {
        const int tr = (int)(c1[i] * 0.25);
        const int ec = (int)(c2[i] * 0.25);
        const int e  = etile * 16 + ec;
        logits[tr][e] = (float)(acc[i] * xinv_lds[tr] * pinv_lds[e]);
    }
    __syncthreads();
#pragma unroll 1
    for (int i = 0; i < 4; ++i) {
        const int tl = w * 4 + i;
        const float l32 = logits[tl][lane];
        float m = l32;
#pragma unroll
        for (int d = 1; d < 64; d <<= 1) {
            float o = __shfl_xor(m, d, 64);
            m = fmaxf(m, o);
        }
        const float dd = l32 - m;
        const float e32 = (float)exp((double)dd);
        float r[8];
#pragma unroll
        for (int j = 0; j < 8; ++j) {
            float rj = __shfl(e32, j, 64);
#pragma unroll
            for (int b = 1; b < 8; ++b)
                rj += __shfl(e32, j + 8 * b, 64);
            r[j] = rj;
        }
        const float S = ((r[0] + r[1]) + (r[2] + r[3])) +
                        ((r[4] + r[5]) + (r[6] + r[7]));
        const float wgt = e32 / S;
        int rank = 0;
#pragma unroll 1
        for (int sdist = 1; sdist < 64; ++sdist) {
            float ow = __shfl_xor(wgt, sdist, 64);
            int j = lane ^ sdist;
            rank += (ow > wgt) || (ow == wgt && j < lane);
        }
        if (rank < TOPK) {
            const int tok = tok0 + tl;
            out[tok * TOPK + rank] = wgt;
            out[NTOK * TOPK + tok * TOPK + rank] = (float)lane;
        }
    }
}

extern "C" void kernel_launch(void* const* d_in, const int* in_sizes, int n_in,
                              void* d_out, int out_size, void* d_ws, size_t ws_size,
                              hipStream_t stream) {
    const float* x     = (const float*)d_in[0];
    const float* proto = (const float*)d_in[1];
    float* out         = (float*)d_out;
    (void)in_sizes; (void)n_in; (void)out_size;

    if (ws_size >= WS_NEEDED) {
        double* pinv = (double*)d_ws;
        int*    plimb = (int*)((char*)d_ws + 512);
        proto_prep_kernel<<<NEXP, 64, 0, stream>>>(proto, pinv, plimb);
        router_i8_kernel<<<NTOK / TB, 256, 0, stream>>>(x, pinv, plimb, out);
    } else {
        router_f64_kernel<<<NTOK / TB, 256, 0, stream>>>(x, proto, out);
    }
}

// Round 14
// 126.836 us; speedup vs baseline: 1.5071x; 1.5071x over previous
//
#include <hip/hip_runtime.h>
#include <math.h>

#define NTOK   16384
#define DIM    2048
#define NEXP   64
#define TOPK   8
#define TB     16          // tokens per block -> grid 1024
#define KC     64          // K chunk
#define NCHUNK (DIM / KC)  // 32
#define XLS    20          // LDS limb-row stride (dwords): 16B-aligned, ~2-deep banks

typedef int    v4i __attribute__((ext_vector_type(4)));
typedef double v4d __attribute__((ext_vector_type(4)));

// ws layout: [0,512) pinv (64 f64); [512, 512+786432) proto limb dwords
#define WS_NEEDED (512 + (size_t)NEXP * 6 * (DIM / 4) * 4)

#define MAGICF 12582912.0f   // 1.5 * 2^23: fma magic for round-to-nearest digit

// x digit scales: Xi = rint(r * 2^(3+7i)), weight 2^-(3+7i), |Xi|<=64
__device__ __constant__ float XSC[6] = {8.f, 1024.f, 131072.f, 16777216.f, 2147483648.f, 274877906944.f};
__device__ __constant__ float XWN[6] = {-0.125f, -9.765625e-04f, -7.62939453125e-06f,
                                        -5.9604644775390625e-08f, -4.656612873077393e-10f,
                                        -3.637978807091713e-12f};
// p digit scales: Yj = rint(r * 2^(9+7j)), weight 2^-(9+7j)
__device__ __constant__ float PSC[6] = {512.f, 65536.f, 8388608.f, 1073741824.f, 137438953472.f, 17592186044416.f};
__device__ __constant__ float PWN[6] = {-1.953125e-03f, -1.52587890625e-05f, -1.1920928955078125e-07f,
                                        -9.31322574615478516e-10f, -7.27595761418342590e-12f,
                                        -5.68434188608080149e-14f};
// class-combine weights 2^(-12-7d), d=0..6
__device__ __constant__ double CWD[7] = {2.44140625e-04, 1.9073486328125e-06, 1.490116119384765625e-08,
                                         1.16415321826934814e-10, 9.09494701772928238e-13,
                                         7.10542735760100186e-15, 5.55111512312578270e-17};

// ---------------- pre-kernel: pinv (f64) + proto limb decomposition (r13-proven) ----------------
__global__ __launch_bounds__(64) void proto_prep_kernel(
    const float* __restrict__ proto, double* __restrict__ pinv,
    int* __restrict__ plimb)
{
    const int e = blockIdx.x, t = threadIdx.x;
    const float* row = proto + (size_t)e * DIM;
    const int k0 = t * 32;
    double s = 0.0;
#pragma unroll
    for (int g = 0; g < 8; ++g) {
        int pk0 = 0, pk1 = 0, pk2 = 0, pk3 = 0, pk4 = 0, pk5 = 0;
#pragma unroll
        for (int b = 0; b < 4; ++b) {
            float f = row[k0 + g * 4 + b];
            s += (double)f * (double)f;
            float r = f;
#pragma unroll
            for (int j = 0; j < 6; ++j) {
                float rd = rintf(r * PSC[j]);
                int   d  = (int)rd;
                r = fmaf(rd, PWN[j], r);
                int byte = (d & 255) << (8 * b);
                if (j == 0) pk0 |= byte; else if (j == 1) pk1 |= byte;
                else if (j == 2) pk2 |= byte;   else if (j == 3) pk3 |= byte;
                else if (j == 4) pk4 |= byte;   else pk5 |= byte;
            }
        }
        const int dw = (k0 + g * 4) >> 2;
        plimb[(e * 6 + 0) * (DIM / 4) + dw] = pk0;
        plimb[(e * 6 + 1) * (DIM / 4) + dw] = pk1;
        plimb[(e * 6 + 2) * (DIM / 4) + dw] = pk2;
        plimb[(e * 6 + 3) * (DIM / 4) + dw] = pk3;
        plimb[(e * 6 + 4) * (DIM / 4) + dw] = pk4;
        plimb[(e * 6 + 5) * (DIM / 4) + dw] = pk5;
    }
#pragma unroll
    for (int d = 1; d < 64; d <<= 1)
        s += __shfl_xor(s, d, 64);
    if (t == 0)
        pinv[e] = 1.0 / fmax(sqrt(s), 1e-12);
}

// ---------------- main: i8-MFMA router, LDS-shared x-limb decomposition ----------------
__global__ __launch_bounds__(256, 2) void router_i8_kernel(
    const float* __restrict__ x, const double* __restrict__ pinv,
    const int* __restrict__ plimb, float* __restrict__ out)
{
    __shared__ __align__(16) int xl[2][6][TB][XLS];  // 15360 B limb panel, dbuf
    __shared__ float  logits[TB][NEXP];              // 4 KiB
    __shared__ double xinv_lds[TB];
    __shared__ double pinv_lds[NEXP];

    const int tid  = threadIdx.x;
    const int lane = tid & 63;
    const int w    = tid >> 6;            // wave = expert tile [16w,16w+16)
    const int tok0 = blockIdx.x * TB;

    // decomp role: 4 floats per thread covers the 16x64 chunk exactly once
    const int td = tid >> 4;              // token 0..15
    const int dw = tid & 15;              // dword group (4 floats) within chunk
    const float* xsrc = x + (size_t)(tok0 + td) * DIM + dw * 4;

    // MFMA role
    const int arow = lane & 15;           // A-row / B-col label
    const int akg  = lane >> 4;           // quarter-wave k-group
    const int ecol = w * 16 + arow;
    const int* bbase = plimb + (size_t)ecol * 6 * (DIM / 4) + akg * 4;

    v4i acc[7];
#pragma unroll
    for (int d = 0; d < 7; ++d) acc[d] = (v4i){0, 0, 0, 0};
    double sumsq = 0.0;

    if (tid < NEXP) pinv_lds[tid] = pinv[tid];

    // decompose 4 floats -> 6 limb-dwords in LDS buf; fuse sumsq
    auto decomp_store = [&](const float4 xq, int buf) {
        sumsq += (double)xq.x * xq.x + (double)xq.y * xq.y
               + (double)xq.z * xq.z + (double)xq.w * xq.w;
        float r0 = xq.x, r1 = xq.y, r2 = xq.z, r3 = xq.w;
#pragma unroll
        for (int i = 0; i < 6; ++i) {
            float y0 = fmaf(r0, XSC[i], MAGICF);    // = MAGIC + rint(r*SC), exact
            float y1 = fmaf(r1, XSC[i], MAGICF);
            float y2 = fmaf(r2, XSC[i], MAGICF);
            float y3 = fmaf(r3, XSC[i], MAGICF);
            r0 = fmaf(y0 - MAGICF, XWN[i], r0);     // exact residual update
            r1 = fmaf(y1 - MAGICF, XWN[i], r1);
            r2 = fmaf(y2 - MAGICF, XWN[i], r2);
            r3 = fmaf(y3 - MAGICF, XWN[i], r3);
            // low byte of y = digit in two's complement
            xl[buf][i][td][dw] = (__float_as_int(y0) & 255)
                               | ((__float_as_int(y1) & 255) << 8)
                               | ((__float_as_int(y2) & 255) << 16)
                               | ((__float_as_int(y3) & 255) << 24);
        }
    };

    // ---- prologue: chunk 0 decomposed into buf0; chunk 1 floats in regs ----
    float4 xv = *(const float4*)(xsrc);
    decomp_store(xv, 0);
    xv = *(const float4*)(xsrc + KC);
    __syncthreads();

    // ---- main loop: 1 barrier/chunk ----
    for (int c = 0; c < NCHUNK; ++c) {
        const int cur = c & 1;

        // A limbs for chunk c from LDS (ready since last barrier)
        v4i af[6];
#pragma unroll
        for (int j = 0; j < 6; ++j)
            af[j] = *(const v4i*)&xl[cur][j][arow][akg * 4];
        // B limbs for chunk c (global, L2-resident)
        v4i bf[6];
#pragma unroll
        for (int j = 0; j < 6; ++j)
            bf[j] = *(const v4i*)(bbase + j * (DIM / 4) + c * 16);

        // decompose chunk c+1 into the other buffer; prefetch chunk c+2 floats
        if (c + 1 < NCHUNK) {
            decomp_store(xv, cur ^ 1);
            if (c + 2 < NCHUNK) xv = *(const float4*)(xsrc + (c + 2) * KC);
        }

        // 26 class MFMAs: class d = i2 + j, exact i32 accumulate
#pragma unroll
        for (int j = 0; j < 6; ++j) {
#pragma unroll
            for (int i2 = 0; i2 < 6; ++i2) {
                if (i2 + j <= 6)
                    acc[i2 + j] = __builtin_amdgcn_mfma_i32_16x16x64_i8(
                        af[i2], bf[j], acc[i2 + j], 0, 0, 0);
            }
        }
        __syncthreads();
    }

    // ---- xinv: butterfly across the 16 threads sharing a token ----
    sumsq += __shfl_xor(sumsq, 1, 16);
    sumsq += __shfl_xor(sumsq, 2, 16);
    sumsq += __shfl_xor(sumsq, 4, 16);
    sumsq += __shfl_xor(sumsq, 8, 16);
    if (dw == 0)
        xinv_lds[td] = 1.0 / fmax(sqrt(sumsq), 1e-12);

    // ---- i32 layout calibration (r13-proven) ----
    const int ones = 0x01010101;
    v4i onesv = (v4i){ones, ones, ones, ones};
    int rp = arow * ones;
    v4i rowv = (v4i){rp, rp, rp, rp};
    v4i c1 = (v4i){0, 0, 0, 0}, c2 = (v4i){0, 0, 0, 0};
    c1 = __builtin_amdgcn_mfma_i32_16x16x64_i8(rowv, onesv, c1, 0, 0, 0);  // 64*row
    c2 = __builtin_amdgcn_mfma_i32_16x16x64_i8(onesv, rowv, c2, 0, 0, 0);  // 64*col
    __syncthreads();

    // ---- combine classes in f64, scale to cosine logits, cast fp32 ----
#pragma unroll
    for (int i = 0; i < 4; ++i) {
        double S = 0.0;
#pragma unroll
        for (int d = 0; d < 7; ++d)
            S = fma((double)acc[d][i], CWD[d], S);
        const int tr = c1[i] >> 6;                 // token-within-tile label
        const int ec = c2[i] >> 6;                 // expert-within-16 label
        const int e  = w * 16 + ec;
        logits[tr][e] = (float)(S * xinv_lds[tr] * pinv_lds[e]);
    }
    __syncthreads();

    // ---- epilogue: np fp32 softmax bit-chain + rank by (w32 desc, idx asc) ----
#pragma unroll 1
    for (int i = 0; i < 4; ++i) {
        const int tl = w * 4 + i;
        const float l32 = logits[tl][lane];

        float m = l32;
#pragma unroll
        for (int d = 1; d < 64; d <<= 1) {
            float o = __shfl_xor(m, d, 64);
            m = fmaxf(m, o);
        }
        const float dd = l32 - m;
        const float e32 = (float)exp((double)dd);

        float r[8];
#pragma unroll
        for (int j = 0; j < 8; ++j) {
            float rj = __shfl(e32, j, 64);
#pragma unroll
            for (int b = 1; b < 8; ++b)
                rj += __shfl(e32, j + 8 * b, 64);
            r[j] = rj;
        }
        const float S = ((r[0] + r[1]) + (r[2] + r[3])) +
                        ((r[4] + r[5]) + (r[6] + r[7]));
        const float wgt = e32 / S;

        int rank = 0;
#pragma unroll 1
        for (int sdist = 1; sdist < 64; ++sdist) {
            float ow = __shfl_xor(wgt, sdist, 64);
            int j = lane ^ sdist;
            rank += (ow > wgt) || (ow == wgt && j < lane);
        }

        if (rank < TOPK) {
            const int tok = tok0 + tl;
            out[tok * TOPK + rank] = wgt;
            out[NTOK * TOPK + tok * TOPK + rank] = (float)lane;
        }
    }
}

// ---------------- fallback: proven r12 f64-MFMA kernel (ws too small) ----------------
__global__ __launch_bounds__(256, 2) void router_f64_kernel(
    const float* __restrict__ x, const float* __restrict__ proto,
    float* __restrict__ out)
{
    __shared__ float  logits[TB][NEXP];
    __shared__ double xinv_lds[TB];
    __shared__ double pinv_lds[NEXP];

    const int tid  = threadIdx.x;
    const int lane = tid & 63;
    const int w    = tid >> 6;
    const int tok0 = blockIdx.x * TB;
    const int etile = w;
    const int arow  = lane & 15;
    const int akg   = lane >> 4;
    const int kbase = akg * 8;

    v4d acc0 = {0., 0., 0., 0.}, acc1 = {0., 0., 0., 0.};
    v4d acc2 = {0., 0., 0., 0.}, acc3 = {0., 0., 0., 0.};
    double sumsq = 0.0, psq = 0.0;

    const float* xrow = x     + (size_t)(tok0 + arow)       * DIM + kbase;
    const float* prow = proto + (size_t)(etile * 16 + arow) * DIM + kbase;

    float4 xa0, xa1, pa0, pa1, xb0, xb1, pb0, pb1;

#define FLOADSET(X0, X1, P0, P1, c) do {                            \
    const float* _xp = xrow + (c) * 32;                             \
    const float* _pp = prow + (c) * 32;                             \
    X0 = *(const float4*)(_xp);  X1 = *(const float4*)(_xp + 4);    \
    P0 = *(const float4*)(_pp);  P1 = *(const float4*)(_pp + 4);    \
    } while (0)
#define FNORMQ(A, B) do {                                           \
    double a0 = (double)A.x, a1 = (double)A.y,                      \
           a2 = (double)A.z, a3 = (double)A.w;                      \
    double u0 = (double)B.x, u1 = (double)B.y,                      \
           u2 = (double)B.z, u3 = (double)B.w;                      \
    sumsq += a0*a0 + a1*a1 + a2*a2 + a3*a3;                         \
    psq   += u0*u0 + u1*u1 + u2*u2 + u3*u3;                         \
    } while (0)
#define FCOMPUTE(X0, X1, P0, P1) do {                               \
    FNORMQ(X0, P0); FNORMQ(X1, P1);                                 \
    acc0 = __builtin_amdgcn_mfma_f64_16x16x4f64((double)X0.x, (double)P0.x, acc0, 0, 0, 0); \
    acc1 = __builtin_amdgcn_mfma_f64_16x16x4f64((double)X0.y, (double)P0.y, acc1, 0, 0, 0); \
    acc2 = __builtin_amdgcn_mfma_f64_16x16x4f64((double)X0.z, (double)P0.z, acc2, 0, 0, 0); \
    acc3 = __builtin_amdgcn_mfma_f64_16x16x4f64((double)X0.w, (double)P0.w, acc3, 0, 0, 0); \
    acc0 = __builtin_amdgcn_mfma_f64_16x16x4f64((double)X1.x, (double)P1.x, acc0, 0, 0, 0); \
    acc1 = __builtin_amdgcn_mfma_f64_16x16x4f64((double)X1.y, (double)P1.y, acc1, 0, 0, 0); \
    acc2 = __builtin_amdgcn_mfma_f64_16x16x4f64((double)X1.z, (double)P1.z, acc2, 0, 0, 0); \
    acc3 = __builtin_amdgcn_mfma_f64_16x16x4f64((double)X1.w, (double)P1.w, acc3, 0, 0, 0); \
    } while (0)

    FLOADSET(xa0, xa1, pa0, pa1, 0);
    for (int c = 0; c < 64; c += 2) {
        FLOADSET(xb0, xb1, pb0, pb1, c + 1);
        FCOMPUTE(xa0, xa1, pa0, pa1);
        if (c + 2 < 64) FLOADSET(xa0, xa1, pa0, pa1, c + 2);
        FCOMPUTE(xb0, xb1, pb0, pb1);
    }
    const v4d acc = (acc0 + acc1) + (acc2 + acc3);

    sumsq += __shfl_xor(sumsq, 16, 64);
    sumsq += __shfl_xor(sumsq, 32, 64);
    psq   += __shfl_xor(psq, 16, 64);
    psq   += __shfl_xor(psq, 32, 64);
    if (akg == 0) {
        xinv_lds[arow]              = 1.0 / fmax(sqrt(sumsq), 1e-12);
        pinv_lds[etile * 16 + arow] = 1.0 / fmax(sqrt(psq), 1e-12);
    }
    v4d c1 = {0., 0., 0., 0.}, c2 = {0., 0., 0., 0.};
    c1 = __builtin_amdgcn_mfma_f64_16x16x4f64((double)arow, 1.0, c1, 0, 0, 0);
    c2 = __builtin_amdgcn_mfma_f64_16x16x4f64(1.0, (double)arow, c2, 0, 0, 0);
    __syncthreads();
#pragma unroll
    for (int i = 0; i < 4; ++i) {
        const int tr = (int)(c1[i] * 0.25);
        const int ec = (int)(c2[i] * 0.25);
        const int e  = etile * 16 + ec;
        logits[tr][e] = (float)(acc[i] * xinv_lds[tr] * pinv_lds[e]);
    }
    __syncthreads();
#pragma unroll 1
    for (int i = 0; i < 4; ++i) {
        const int tl = w * 4 + i;
        const float l32 = logits[tl][lane];
        float m = l32;
#pragma unroll
        for (int d = 1; d < 64; d <<= 1) {
            float o = __shfl_xor(m, d, 64);
            m = fmaxf(m, o);
        }
        const float dd = l32 - m;
        const float e32 = (float)exp((double)dd);
        float r[8];
#pragma unroll
        for (int j = 0; j < 8; ++j) {
            float rj = __shfl(e32, j, 64);
#pragma unroll
            for (int b = 1; b < 8; ++b)
                rj += __shfl(e32, j + 8 * b, 64);
            r[j] = rj;
        }
        const float S = ((r[0] + r[1]) + (r[2] + r[3])) +
                        ((r[4] + r[5]) + (r[6] + r[7]));
        const float wgt = e32 / S;
        int rank = 0;
#pragma unroll 1
        for (int sdist = 1; sdist < 64; ++sdist) {
            float ow = __shfl_xor(wgt, sdist, 64);
            int j = lane ^ sdist;
            rank += (ow > wgt) || (ow == wgt && j < lane);
        }
        if (rank < TOPK) {
            const int tok = tok0 + tl;
            out[tok * TOPK + rank] = wgt;
            out[NTOK * TOPK + tok * TOPK + rank] = (float)lane;
        }
    }
}

extern "C" void kernel_launch(void* const* d_in, const int* in_sizes, int n_in,
                              void* d_out, int out_size, void* d_ws, size_t ws_size,
                              hipStream_t stream) {
    const float* x     = (const float*)d_in[0];
    const float* proto = (const float*)d_in[1];
    float* out         = (float*)d_out;
    (void)in_sizes; (void)n_in; (void)out_size;

    if (ws_size >= WS_NEEDED) {
        double* pinv = (double*)d_ws;
        int*    plimb = (int*)((char*)d_ws + 512);
        proto_prep_kernel<<<NEXP, 64, 0, stream>>>(proto, pinv, plimb);
        router_i8_kernel<<<NTOK / TB, 256, 0, stream>>>(x, pinv, plimb, out);
    } else {
        router_f64_kernel<<<NTOK / TB, 256, 0, stream>>>(x, proto, out);
    }
}